// Round 3
// baseline (435.805 us; speedup 1.0000x reference)
//
#include <hip/hip_runtime.h>
#include <hip/hip_bf16.h>

#define B_   8
#define N_   512
#define IND  256
#define H_   4
#define PH   32
#define OD   128   // H_*PH
#define TI   4     // targets per block (attn)
#define TJ   64    // source tile (attn)
#define XLS_STRIDE 132  // 128 + 4 pad

// ---------------------------------------------------------------------------
// Kernel 1: xl = x@Wl + bl ; xr = x@Wr + br  (fp32 in, fp32 out to ws)
// grid 512, block 256; 8 rows per block.
// thread: which = t>>7 (0:l, 1:r), rg = (t>>6)&1 (4 rows), og = t&63 (2 cols)
// xs reads are wave-uniform (broadcast); W loads coalesced float2.
// ---------------------------------------------------------------------------
__global__ __launch_bounds__(256, 2) void proj_kernel(
    const float* __restrict__ x,
    const float* __restrict__ Wl, const float* __restrict__ bl,
    const float* __restrict__ Wr, const float* __restrict__ br,
    float* __restrict__ xl, float* __restrict__ xr)
{
    __shared__ float xs[8 * IND];
    const int t = threadIdx.x;
    const int row0 = blockIdx.x * 8;

    const float4* xp4 = (const float4*)(x + (size_t)row0 * IND);
    float4* xs4 = (float4*)xs;
    #pragma unroll
    for (int k = 0; k < 2; ++k)
        xs4[t + k * 256] = xp4[t + k * 256];
    __syncthreads();

    const int which = t >> 7;
    const int rg = (t >> 6) & 1;
    const int og = t & 63;
    const int o0 = og * 2;
    const int r0 = rg * 4;
    const float* W  = which ? Wr : Wl;
    const float* bb = which ? br : bl;

    float acc0[4], acc1[4];
    #pragma unroll
    for (int r = 0; r < 4; ++r) { acc0[r] = 0.f; acc1[r] = 0.f; }

    for (int k = 0; k < IND; k += 4) {
        float wf0[4], wf1[4];
        #pragma unroll
        for (int kk = 0; kk < 4; ++kk) {
            float2 wv = *(const float2*)(W + (size_t)(k + kk) * OD + o0);
            wf0[kk] = wv.x;
            wf1[kk] = wv.y;
        }
        float xv[4][4];
        #pragma unroll
        for (int r = 0; r < 4; ++r)
            *(float4*)(xv[r]) = *(const float4*)(&xs[(r0 + r) * IND + k]);
        #pragma unroll
        for (int kk = 0; kk < 4; ++kk)
            #pragma unroll
            for (int r = 0; r < 4; ++r) {
                acc0[r] = fmaf(xv[r][kk], wf0[kk], acc0[r]);
                acc1[r] = fmaf(xv[r][kk], wf1[kk], acc1[r]);
            }
    }

    const float bv0 = bb[o0];
    const float bv1 = bb[o0 + 1];
    float* dst = which ? xr : xl;
    #pragma unroll
    for (int r = 0; r < 4; ++r) {
        float2 v = make_float2(acc0[r] + bv0, acc1[r] + bv1);
        *(float2*)(&dst[(size_t)(row0 + r0 + r) * OD + o0]) = v;
    }
}

// ---------------------------------------------------------------------------
// Kernel 2: masked-softmax attention aggregate.
// grid 1024 (= B * N/TI), block 256  ->  4 blocks/CU (LDS-capped), ~50% occ.
// thread: q = t&15 (16 j-slices), h = (t>>4)&3, il = t>>6 (target, = wave id).
// leaky(s) = 0.6 s + 0.4 |s|  ->  e = 0.6(dr+dl) + 0.4 * sum_c att*|xr+xl|
// e2 uses 4 interleaved accumulators to break the 32-FMA dependency chain.
// Epilogue: reduce-scatter butterfly over the 16 q-lanes (30 shuffles, each
// lane ends holding exactly its 2 output columns c = 2q, 2q+1).
// ---------------------------------------------------------------------------
__global__ __launch_bounds__(256, 4) void attn_kernel(
    const int* __restrict__ adj, const float* __restrict__ att,
    const float* __restrict__ bias,
    const float* __restrict__ xl, const float* __restrict__ xr,
    float* __restrict__ out)
{
    __shared__ float xls[TJ * XLS_STRIDE];  // 33.8 KB
    __shared__ float masks[TJ * TI];        // 1 KB   [jj][il]
    __shared__ float dls[TJ * H_];          // 1 KB   [jj][h]

    const int t = threadIdx.x;
    const int b  = blockIdx.x >> 7;
    const int i0 = (blockIdx.x & 127) * TI;
    const int q  = t & 15;
    const int h  = (t >> 4) & 3;
    const int il = t >> 6;
    const int ig = i0 + il;

    float attv[PH], xrv[PH];
    {
        const float* xrp = xr + ((size_t)(b * N_ + ig)) * OD + h * PH;
        #pragma unroll
        for (int k = 0; k < PH; k += 4) {
            float4 v = *(const float4*)(xrp + k);
            xrv[k] = v.x; xrv[k+1] = v.y; xrv[k+2] = v.z; xrv[k+3] = v.w;
        }
        const float* ap = att + h * PH;
        #pragma unroll
        for (int k = 0; k < PH; ++k) attv[k] = ap[k];
    }
    float dr = 0.f;
    #pragma unroll
    for (int k = 0; k < PH; ++k) dr = fmaf(attv[k], xrv[k], dr);
    const float c0 = 0.6f * dr;

    float acc[PH];
    #pragma unroll
    for (int k = 0; k < PH; ++k) acc[k] = 0.f;
    float sumw = 0.f;

    const float* xlb = xl + (size_t)b * N_ * OD;
    const int* adjb  = adj + (size_t)b * N_ * N_;

    for (int tile = 0; tile < N_ / TJ; ++tile) {
        const int j0 = tile * TJ;
        __syncthreads();
        // stage xl tile: 64 rows x 128 fp32, padded stride
        #pragma unroll
        for (int k = 0; k < 8; ++k) {
            int idx = t + k * 256;          // float4 units, 0..2047
            int jj = idx >> 5, m = idx & 31;
            *(float4*)(&xls[jj * XLS_STRIDE + m * 4]) =
                *(const float4*)(xlb + (size_t)(j0 + jj) * OD + m * 4);
        }
        // adjacency mask: m[i,j] = adj[b][j][i] != 0, diagonal forced 1
        {
            int jj = t >> 2, ii = t & 3;
            int jg2 = j0 + jj, ig2 = i0 + ii;
            int a = adjb[(size_t)jg2 * N_ + ig2];
            masks[t] = (a != 0 || jg2 == ig2) ? 1.f : 0.f;
        }
        __syncthreads();
        // dl[jj,h] = sum_c att[h,c]*xl[jj,h,c] ; bijective thread->entry map
        {
            int jj = il * 16 + q;
            const float* p = &xls[jj * XLS_STRIDE + h * PH];
            float d0 = 0.f, d1 = 0.f, d2 = 0.f, d3 = 0.f;
            #pragma unroll
            for (int k = 0; k < PH; k += 4) {
                d0 = fmaf(attv[k+0], p[k+0], d0);
                d1 = fmaf(attv[k+1], p[k+1], d1);
                d2 = fmaf(attv[k+2], p[k+2], d2);
                d3 = fmaf(attv[k+3], p[k+3], d3);
            }
            dls[jj * H_ + h] = (d0 + d1) + (d2 + d3);
        }
        __syncthreads();
        #pragma unroll 2
        for (int u = 0; u < 4; ++u) {
            const int jj = q + u * 16;
            const float* vrow = &xls[jj * XLS_STRIDE + h * PH];
            float v[PH];
            #pragma unroll
            for (int k = 0; k < PH; k += 4) {
                float4 w4 = *(const float4*)(vrow + k);
                v[k] = w4.x; v[k+1] = w4.y; v[k+2] = w4.z; v[k+3] = w4.w;
            }
            float e2a = 0.f, e2b = 0.f, e2c = 0.f, e2d = 0.f;
            #pragma unroll
            for (int k = 0; k < PH; k += 4) {
                e2a = fmaf(attv[k+0], fabsf(xrv[k+0] + v[k+0]), e2a);
                e2b = fmaf(attv[k+1], fabsf(xrv[k+1] + v[k+1]), e2b);
                e2c = fmaf(attv[k+2], fabsf(xrv[k+2] + v[k+2]), e2c);
                e2d = fmaf(attv[k+3], fabsf(xrv[k+3] + v[k+3]), e2d);
            }
            float e2 = (e2a + e2b) + (e2c + e2d);
            float e = fmaf(0.6f, dls[jj * H_ + h], c0);
            e = fmaf(0.4f, e2, e);
            float w = masks[jj * TI + il] * __expf(e);
            sumw += w;
            #pragma unroll
            for (int k = 0; k < PH; ++k) acc[k] = fmaf(w, v[k], acc[k]);
        }
    }

    // sumw: full butterfly over the 16 q-lanes
    #pragma unroll
    for (int d = 1; d < 16; d <<= 1) sumw += __shfl_xor(sumw, d);
    const float inv = 1.f / sumw;

    // acc: reduce-scatter butterfly. After level d, lane q holds the c-range
    // selected by the corresponding bit of q; final: lane q holds c=2q,2q+1.
    float r8[16];
    {
        const bool hi = (q & 8) != 0;
        #pragma unroll
        for (int m = 0; m < 16; ++m) {
            float send = hi ? acc[m] : acc[16 + m];
            float keep = hi ? acc[16 + m] : acc[m];
            r8[m] = keep + __shfl_xor(send, 8);
        }
    }
    float r4[8];
    {
        const bool hi = (q & 4) != 0;
        #pragma unroll
        for (int m = 0; m < 8; ++m) {
            float send = hi ? r8[m] : r8[8 + m];
            float keep = hi ? r8[8 + m] : r8[m];
            r4[m] = keep + __shfl_xor(send, 4);
        }
    }
    float r2[4];
    {
        const bool hi = (q & 2) != 0;
        #pragma unroll
        for (int m = 0; m < 4; ++m) {
            float send = hi ? r4[m] : r4[4 + m];
            float keep = hi ? r4[4 + m] : r4[m];
            r2[m] = keep + __shfl_xor(send, 2);
        }
    }
    float r1[2];
    {
        const bool hi = (q & 1) != 0;
        #pragma unroll
        for (int m = 0; m < 2; ++m) {
            float send = hi ? r2[m] : r2[2 + m];
            float keep = hi ? r2[2 + m] : r2[m];
            r1[m] = keep + __shfl_xor(send, 1);
        }
    }

    const int c0i = q * 2;
    float* op = out + ((size_t)(b * N_ + ig)) * OD + h * PH;
    op[c0i]     = fmaf(r1[0], inv, bias[h * PH + c0i]);
    op[c0i + 1] = fmaf(r1[1], inv, bias[h * PH + c0i + 1]);
}

extern "C" void kernel_launch(void* const* d_in, const int* in_sizes, int n_in,
                              void* d_out, int out_size, void* d_ws, size_t ws_size,
                              hipStream_t stream) {
    // Dtype settled by round-1/round-2 A/B: float tensors are fp32.
    const float* x    = (const float*)d_in[0];
    const int*   adj  = (const int*)d_in[1];
    const float* Wl   = (const float*)d_in[2];
    const float* bl   = (const float*)d_in[3];
    const float* Wr   = (const float*)d_in[4];
    const float* br   = (const float*)d_in[5];
    const float* att  = (const float*)d_in[6];
    const float* bias = (const float*)d_in[7];
    float* out = (float*)d_out;

    float* xl = (float*)d_ws;                    // 2 MB
    float* xr = xl + (size_t)B_ * N_ * OD;       // 2 MB

    proj_kernel<<<512, 256, 0, stream>>>(x, Wl, bl, Wr, br, xl, xr);
    attn_kernel<<<1024, 256, 0, stream>>>(adj, att, bias, xl, xr, out);
}

// Round 4
// 139.197 us; speedup vs baseline: 3.1308x; 3.1308x over previous
//
#include <hip/hip_runtime.h>
#include <hip/hip_bf16.h>

#define B_   8
#define N_   512
#define IND  256
#define H_   4
#define PH   32
#define OD   128   // H_*PH
#define TI   4     // targets per block (attn)
#define TJ   64    // source tile (attn)
#define XLS_STRIDE 132  // 128 + 4 pad

// ---------------------------------------------------------------------------
// Kernel 1: xl = x@Wl + bl ; xr = x@Wr + br  (fp32 in, fp32 out to ws)
// grid 512, block 256; 8 rows per block.
// ---------------------------------------------------------------------------
__global__ __launch_bounds__(256, 2) void proj_kernel(
    const float* __restrict__ x,
    const float* __restrict__ Wl, const float* __restrict__ bl,
    const float* __restrict__ Wr, const float* __restrict__ br,
    float* __restrict__ xl, float* __restrict__ xr)
{
    __shared__ float xs[8 * IND];
    const int t = threadIdx.x;
    const int row0 = blockIdx.x * 8;

    const float4* xp4 = (const float4*)(x + (size_t)row0 * IND);
    float4* xs4 = (float4*)xs;
    #pragma unroll
    for (int k = 0; k < 2; ++k)
        xs4[t + k * 256] = xp4[t + k * 256];
    __syncthreads();

    const int which = t >> 7;
    const int rg = (t >> 6) & 1;
    const int og = t & 63;
    const int o0 = og * 2;
    const int r0 = rg * 4;
    const float* W  = which ? Wr : Wl;
    const float* bb = which ? br : bl;

    float acc0[4], acc1[4];
    #pragma unroll
    for (int r = 0; r < 4; ++r) { acc0[r] = 0.f; acc1[r] = 0.f; }

    for (int k = 0; k < IND; k += 4) {
        float wf0[4], wf1[4];
        #pragma unroll
        for (int kk = 0; kk < 4; ++kk) {
            float2 wv = *(const float2*)(W + (size_t)(k + kk) * OD + o0);
            wf0[kk] = wv.x;
            wf1[kk] = wv.y;
        }
        float xv[4][4];
        #pragma unroll
        for (int r = 0; r < 4; ++r)
            *(float4*)(xv[r]) = *(const float4*)(&xs[(r0 + r) * IND + k]);
        #pragma unroll
        for (int kk = 0; kk < 4; ++kk)
            #pragma unroll
            for (int r = 0; r < 4; ++r) {
                acc0[r] = fmaf(xv[r][kk], wf0[kk], acc0[r]);
                acc1[r] = fmaf(xv[r][kk], wf1[kk], acc1[r]);
            }
    }

    const float bv0 = bb[o0];
    const float bv1 = bb[o0 + 1];
    float* dst = which ? xr : xl;
    #pragma unroll
    for (int r = 0; r < 4; ++r) {
        float2 v = make_float2(acc0[r] + bv0, acc1[r] + bv1);
        *(float2*)(&dst[(size_t)(row0 + r0 + r) * OD + o0]) = v;
    }
}

// ---------------------------------------------------------------------------
// Kernel 2: masked-softmax attention aggregate.
// grid 1024 (= B * N/TI), block 256 -> 4 blocks/CU (LDS-capped ~50% occ).
// thread: ch = t&1 (c-half of 16), q = (t>>1)&7 (8 j-slices), h = (t>>4)&3,
//         il = t>>6 (target, = wave id).
// c-split halves per-thread arrays (64 floats) -> no spill at (256,2);
// round-3 lesson: (256,4) forced scratch spill -> 1.5 GB HBM traffic.
// leaky(s) = 0.6 s + 0.4|s| -> e = 0.6(dr+dl) + 0.4*sum_c att*|xr+xl|.
// e2 completed across the lane pair with one __shfl_xor(.,1) per j.
// ---------------------------------------------------------------------------
__global__ __launch_bounds__(256, 2) void attn_kernel(
    const int* __restrict__ adj, const float* __restrict__ att,
    const float* __restrict__ bias,
    const float* __restrict__ xl, const float* __restrict__ xr,
    float* __restrict__ out)
{
    __shared__ float xls[TJ * XLS_STRIDE];  // 33.8 KB
    __shared__ float masks[TJ * TI];        // 1 KB   [jj][il]
    __shared__ float dls[TJ * H_];          // 1 KB   [jj][h]

    const int t = threadIdx.x;
    const int b  = blockIdx.x >> 7;
    const int i0 = (blockIdx.x & 127) * TI;
    const int ch = t & 1;
    const int q  = (t >> 1) & 7;
    const int h  = (t >> 4) & 3;
    const int il = t >> 6;
    const int ig = i0 + il;
    const int cbase = h * PH + ch * 16;

    float attv[16], xrv[16];
    {
        const float* xrp = xr + ((size_t)(b * N_ + ig)) * OD + cbase;
        #pragma unroll
        for (int k = 0; k < 16; k += 4) {
            float4 v = *(const float4*)(xrp + k);
            xrv[k] = v.x; xrv[k+1] = v.y; xrv[k+2] = v.z; xrv[k+3] = v.w;
        }
        const float* ap = att + cbase;
        #pragma unroll
        for (int k = 0; k < 16; ++k) attv[k] = ap[k];
    }
    float drh = 0.f;
    #pragma unroll
    for (int k = 0; k < 16; ++k) drh = fmaf(attv[k], xrv[k], drh);
    const float dr = drh + __shfl_xor(drh, 1);
    const float c0 = 0.6f * dr;

    float acc[16];
    #pragma unroll
    for (int k = 0; k < 16; ++k) acc[k] = 0.f;
    float sumw = 0.f;

    const float* xlb = xl + (size_t)b * N_ * OD;
    const int* adjb  = adj + (size_t)b * N_ * N_;

    for (int tile = 0; tile < N_ / TJ; ++tile) {
        const int j0 = tile * TJ;
        __syncthreads();
        // stage xl tile: 64 rows x 128 fp32, padded stride
        #pragma unroll
        for (int k = 0; k < 8; ++k) {
            int idx = t + k * 256;          // float4 units, 0..2047
            int jj = idx >> 5, m = idx & 31;
            *(float4*)(&xls[jj * XLS_STRIDE + m * 4]) =
                *(const float4*)(xlb + (size_t)(j0 + jj) * OD + m * 4);
        }
        // adjacency mask: m[i,j] = adj[b][j][i] != 0, diagonal forced 1
        {
            int jj = t >> 2, ii = t & 3;
            int jg2 = j0 + jj, ig2 = i0 + ii;
            int a = adjb[(size_t)jg2 * N_ + ig2];
            masks[t] = (a != 0 || jg2 == ig2) ? 1.f : 0.f;
        }
        __syncthreads();
        // dl[jj,h]: lane pair (q,ch) covers jj0=il*16+q*2 and jj0+1 for its h
        {
            const int jj0 = il * 16 + q * 2;
            const float* p0 = &xls[jj0 * XLS_STRIDE + cbase];
            float s0a = 0.f, s0b = 0.f, s1a = 0.f, s1b = 0.f;
            #pragma unroll
            for (int k = 0; k < 16; k += 2) {
                s0a = fmaf(attv[k],   p0[k],   s0a);
                s0b = fmaf(attv[k+1], p0[k+1], s0b);
                s1a = fmaf(attv[k],   p0[XLS_STRIDE + k],   s1a);
                s1b = fmaf(attv[k+1], p0[XLS_STRIDE + k+1], s1b);
            }
            float s0 = s0a + s0b, s1 = s1a + s1b;
            float o0 = s0 + __shfl_xor(s0, 1);
            float o1 = s1 + __shfl_xor(s1, 1);
            dls[(jj0 + ch) * H_ + h] = ch ? o1 : o0;
        }
        __syncthreads();
        #pragma unroll 2
        for (int u = 0; u < 8; ++u) {
            const int jj = q + u * 8;
            const float* vrow = &xls[jj * XLS_STRIDE + cbase];
            float v[16];
            #pragma unroll
            for (int k = 0; k < 16; k += 4) {
                float4 w4 = *(const float4*)(vrow + k);
                v[k] = w4.x; v[k+1] = w4.y; v[k+2] = w4.z; v[k+3] = w4.w;
            }
            float ea = 0.f, eb = 0.f, ec = 0.f, ed = 0.f;
            #pragma unroll
            for (int k = 0; k < 16; k += 4) {
                ea = fmaf(attv[k+0], fabsf(xrv[k+0] + v[k+0]), ea);
                eb = fmaf(attv[k+1], fabsf(xrv[k+1] + v[k+1]), eb);
                ec = fmaf(attv[k+2], fabsf(xrv[k+2] + v[k+2]), ec);
                ed = fmaf(attv[k+3], fabsf(xrv[k+3] + v[k+3]), ed);
            }
            float e2h = (ea + eb) + (ec + ed);
            float e2 = e2h + __shfl_xor(e2h, 1);
            float e = fmaf(0.6f, dls[jj * H_ + h], c0);
            e = fmaf(0.4f, e2, e);
            float w = masks[jj * TI + il] * __expf(e);
            sumw += w;
            #pragma unroll
            for (int k = 0; k < 16; ++k) acc[k] = fmaf(w, v[k], acc[k]);
        }
    }

    // sumw: reduce over the 8 q-lanes (xor 2,4,8); ch copies are identical.
    sumw += __shfl_xor(sumw, 2);
    sumw += __shfl_xor(sumw, 4);
    sumw += __shfl_xor(sumw, 8);
    const float inv = 1.f / sumw;

    // acc: 3-level reduce-scatter over q; lane ends holding c = cbase + 2q.
    float r8[8];
    {
        const bool hi = (q & 4) != 0;
        #pragma unroll
        for (int m = 0; m < 8; ++m) {
            float send = hi ? acc[m] : acc[8 + m];
            float keep = hi ? acc[8 + m] : acc[m];
            r8[m] = keep + __shfl_xor(send, 8);
        }
    }
    float r4[4];
    {
        const bool hi = (q & 2) != 0;
        #pragma unroll
        for (int m = 0; m < 4; ++m) {
            float send = hi ? r4[0] : r4[0]; // placeholder avoided below
            (void)send;
            float s2 = hi ? r8[m] : r8[4 + m];
            float kp = hi ? r8[4 + m] : r8[m];
            r4[m] = kp + __shfl_xor(s2, 4);
        }
    }
    float r2[2];
    {
        const bool hi = (q & 1) != 0;
        #pragma unroll
        for (int m = 0; m < 2; ++m) {
            float s2 = hi ? r4[m] : r4[2 + m];
            float kp = hi ? r4[2 + m] : r4[m];
            r2[m] = kp + __shfl_xor(s2, 2);
        }
    }

    const int c = cbase + q * 2;
    float* op = out + ((size_t)(b * N_ + ig)) * OD;
    op[c]     = fmaf(r2[0], inv, bias[c]);
    op[c + 1] = fmaf(r2[1], inv, bias[c + 1]);
}

extern "C" void kernel_launch(void* const* d_in, const int* in_sizes, int n_in,
                              void* d_out, int out_size, void* d_ws, size_t ws_size,
                              hipStream_t stream) {
    const float* x    = (const float*)d_in[0];
    const int*   adj  = (const int*)d_in[1];
    const float* Wl   = (const float*)d_in[2];
    const float* bl   = (const float*)d_in[3];
    const float* Wr   = (const float*)d_in[4];
    const float* br   = (const float*)d_in[5];
    const float* att  = (const float*)d_in[6];
    const float* bias = (const float*)d_in[7];
    float* out = (float*)d_out;

    float* xl = (float*)d_ws;                    // 2 MB
    float* xr = xl + (size_t)B_ * N_ * OD;       // 2 MB

    proj_kernel<<<512, 256, 0, stream>>>(x, Wl, bl, Wr, br, xl, xr);
    attn_kernel<<<1024, 256, 0, stream>>>(adj, att, bias, xl, xr, out);
}

// Round 5
// 132.706 us; speedup vs baseline: 3.2840x; 1.0489x over previous
//
#include <hip/hip_runtime.h>
#include <hip/hip_bf16.h>

#define B_   8
#define N_   512
#define IND  256
#define H_   4
#define PH   32
#define OD   128   // H_*PH
#define TI   4     // targets per block (attn)
#define TJ   64    // source tile (attn)
#define XLS_STRIDE 132  // 128 + 4 pad

// ---------------------------------------------------------------------------
// Kernel 1: xl = x@Wl + bl ; xr = x@Wr + br  plus fused rank-1 parts
//   dl[n,h] = sum_c att[h,c] * xl[n,h,c]   (which=0 waves)
//   dr[n,h] = sum_c att[h,c] * xr[n,h,c]   (which=1 waves)
// grid 512, block 256; 8 rows per block.
// thread: which = t>>7 (0:l, 1:r), rg = (t>>6)&1 (4 rows), og = t&63 (2 cols).
// Lane id within wave == og, so shfl_xor(1,2,4,8) reduces the 16-lane h-group.
// ---------------------------------------------------------------------------
__global__ __launch_bounds__(256, 2) void proj_kernel(
    const float* __restrict__ x,
    const float* __restrict__ Wl, const float* __restrict__ bl,
    const float* __restrict__ Wr, const float* __restrict__ br,
    const float* __restrict__ att,
    float* __restrict__ xl, float* __restrict__ xr,
    float* __restrict__ dl, float* __restrict__ dr)
{
    __shared__ float xs[8 * IND];
    const int t = threadIdx.x;
    const int row0 = blockIdx.x * 8;

    const float4* xp4 = (const float4*)(x + (size_t)row0 * IND);
    float4* xs4 = (float4*)xs;
    #pragma unroll
    for (int k = 0; k < 2; ++k)
        xs4[t + k * 256] = xp4[t + k * 256];
    __syncthreads();

    const int which = t >> 7;
    const int rg = (t >> 6) & 1;
    const int og = t & 63;
    const int o0 = og * 2;
    const int r0 = rg * 4;
    const float* W  = which ? Wr : Wl;
    const float* bb = which ? br : bl;

    float acc0[4], acc1[4];
    #pragma unroll
    for (int r = 0; r < 4; ++r) { acc0[r] = 0.f; acc1[r] = 0.f; }

    for (int k = 0; k < IND; k += 4) {
        float wf0[4], wf1[4];
        #pragma unroll
        for (int kk = 0; kk < 4; ++kk) {
            float2 wv = *(const float2*)(W + (size_t)(k + kk) * OD + o0);
            wf0[kk] = wv.x;
            wf1[kk] = wv.y;
        }
        float xv[4][4];
        #pragma unroll
        for (int r = 0; r < 4; ++r)
            *(float4*)(xv[r]) = *(const float4*)(&xs[(r0 + r) * IND + k]);
        #pragma unroll
        for (int kk = 0; kk < 4; ++kk)
            #pragma unroll
            for (int r = 0; r < 4; ++r) {
                acc0[r] = fmaf(xv[r][kk], wf0[kk], acc0[r]);
                acc1[r] = fmaf(xv[r][kk], wf1[kk], acc1[r]);
            }
    }

    const float bv0 = bb[o0];
    const float bv1 = bb[o0 + 1];
    const float a0 = att[o0];
    const float a1 = att[o0 + 1];
    float* dst = which ? xr : xl;
    float* dp  = which ? dr : dl;
    float dcon[4];
    #pragma unroll
    for (int r = 0; r < 4; ++r) {
        float y0 = acc0[r] + bv0;
        float y1 = acc1[r] + bv1;
        *(float2*)(&dst[(size_t)(row0 + r0 + r) * OD + o0]) = make_float2(y0, y1);
        dcon[r] = fmaf(a0, y0, a1 * y1);
    }
    // reduce dcon over the 16 og-lanes sharing h = og>>4 (lane id == og)
    #pragma unroll
    for (int m = 1; m < 16; m <<= 1) {
        #pragma unroll
        for (int r = 0; r < 4; ++r)
            dcon[r] += __shfl_xor(dcon[r], m);
    }
    if ((og & 15) == 0) {
        const int h = og >> 4;
        #pragma unroll
        for (int r = 0; r < 4; ++r)
            dp[(size_t)(row0 + r0 + r) * H_ + h] = dcon[r];
    }
}

// ---------------------------------------------------------------------------
// Kernel 2: masked-softmax attention aggregate.
// grid 1024 (= B * N/TI), block 256 -> 4 blocks/CU (LDS ~35 KB).
// thread: ch = t&1 (c-half), q = (t>>1)&7 (8 j-slices), il = (t>>4)&3 (target),
//         h = t>>6 (head == wave id).
// il absent from the LDS v-address -> 4-lane same-address broadcast (free);
// cluster bank groups {q+4ch+k} are all-distinct -> conflict-free reads.
// dl/dr precomputed in proj (round-4's in-kernel dl section was the 7.4M
// bank-conflict source). e = 0.6(dr+dl) + 0.4*sum_c att*|xr+xl|.
// ---------------------------------------------------------------------------
__global__ __launch_bounds__(256, 2) void attn_kernel(
    const int* __restrict__ adj, const float* __restrict__ att,
    const float* __restrict__ bias,
    const float* __restrict__ xl, const float* __restrict__ xr,
    const float* __restrict__ dl, const float* __restrict__ dr,
    float* __restrict__ out)
{
    __shared__ float xls[TJ * XLS_STRIDE];  // 33.8 KB
    __shared__ float masks[TJ * TI];        // 1 KB   [jj][il]

    const int t = threadIdx.x;
    const int b  = blockIdx.x >> 7;
    const int i0 = (blockIdx.x & 127) * TI;
    const int ch = t & 1;
    const int q  = (t >> 1) & 7;
    const int il = (t >> 4) & 3;
    const int h  = t >> 6;
    const int ig = i0 + il;
    const int cbase = h * PH + ch * 16;

    float attv[16], xrv[16];
    {
        const float* xrp = xr + ((size_t)(b * N_ + ig)) * OD + cbase;
        #pragma unroll
        for (int k = 0; k < 16; k += 4) {
            float4 v = *(const float4*)(xrp + k);
            xrv[k] = v.x; xrv[k+1] = v.y; xrv[k+2] = v.z; xrv[k+3] = v.w;
        }
        const float* ap = att + cbase;
        #pragma unroll
        for (int k = 0; k < 16; ++k) attv[k] = ap[k];
    }
    const float c0 = 0.6f * dr[((size_t)(b * N_ + ig)) * H_ + h];

    float acc[16];
    #pragma unroll
    for (int k = 0; k < 16; ++k) acc[k] = 0.f;
    float sumw = 0.f;

    const float* xlb = xl + (size_t)b * N_ * OD;
    const float* dlb = dl + (size_t)b * N_ * H_;
    const int* adjb  = adj + (size_t)b * N_ * N_;

    for (int tile = 0; tile < N_ / TJ; ++tile) {
        const int j0 = tile * TJ;
        __syncthreads();
        // stage xl tile: 64 rows x 128 fp32, padded stride (cluster-clean)
        #pragma unroll
        for (int k = 0; k < 8; ++k) {
            int idx = t + k * 256;          // float4 units, 0..2047
            int jj = idx >> 5, m = idx & 31;
            *(float4*)(&xls[jj * XLS_STRIDE + m * 4]) =
                *(const float4*)(xlb + (size_t)(j0 + jj) * OD + m * 4);
        }
        // adjacency mask: m[i,j] = adj[b][j][i] != 0, diagonal forced 1
        {
            int jj = t >> 2, ii = t & 3;
            int jg2 = j0 + jj, ig2 = i0 + ii;
            int a = adjb[(size_t)jg2 * N_ + ig2];
            masks[t] = (a != 0 || jg2 == ig2) ? 1.f : 0.f;
        }
        __syncthreads();
        // prefetch this tile's dl values (8 scalar L2-hot loads, issued early)
        float dlv[8];
        #pragma unroll
        for (int u = 0; u < 8; ++u)
            dlv[u] = dlb[(size_t)(j0 + q + u * 8) * H_ + h];
        #pragma unroll 2
        for (int u = 0; u < 8; ++u) {
            const int jj = q + u * 8;
            const float* vrow = &xls[jj * XLS_STRIDE + cbase];
            float v[16];
            #pragma unroll
            for (int k = 0; k < 16; k += 4) {
                float4 w4 = *(const float4*)(vrow + k);
                v[k] = w4.x; v[k+1] = w4.y; v[k+2] = w4.z; v[k+3] = w4.w;
            }
            float ea = 0.f, eb = 0.f, ec = 0.f, ed = 0.f;
            #pragma unroll
            for (int k = 0; k < 16; k += 4) {
                ea = fmaf(attv[k+0], fabsf(xrv[k+0] + v[k+0]), ea);
                eb = fmaf(attv[k+1], fabsf(xrv[k+1] + v[k+1]), eb);
                ec = fmaf(attv[k+2], fabsf(xrv[k+2] + v[k+2]), ec);
                ed = fmaf(attv[k+3], fabsf(xrv[k+3] + v[k+3]), ed);
            }
            float e2h = (ea + eb) + (ec + ed);
            float e2 = e2h + __shfl_xor(e2h, 1);      // DPP quad-perm, cheap
            float e = fmaf(0.6f, dlv[u], c0);
            e = fmaf(0.4f, e2, e);
            float w = masks[jj * TI + il] * __expf(e);
            sumw += w;
            #pragma unroll
            for (int k = 0; k < 16; ++k) acc[k] = fmaf(w, v[k], acc[k]);
        }
    }

    // sumw: reduce over the 8 q-lanes (bits 1-3); ch copies identical.
    sumw += __shfl_xor(sumw, 2);
    sumw += __shfl_xor(sumw, 4);
    sumw += __shfl_xor(sumw, 8);
    const float inv = 1.f / sumw;

    // acc: 3-level reduce-scatter over q; lane ends holding c = cbase + 2q.
    float r8[8];
    {
        const bool hi = (q & 4) != 0;
        #pragma unroll
        for (int m = 0; m < 8; ++m) {
            float send = hi ? acc[m] : acc[8 + m];
            float keep = hi ? acc[8 + m] : acc[m];
            r8[m] = keep + __shfl_xor(send, 8);
        }
    }
    float r4[4];
    {
        const bool hi = (q & 2) != 0;
        #pragma unroll
        for (int m = 0; m < 4; ++m) {
            float send = hi ? r8[m] : r8[4 + m];
            float keep = hi ? r8[4 + m] : r8[m];
            r4[m] = keep + __shfl_xor(send, 4);
        }
    }
    float r2[2];
    {
        const bool hi = (q & 1) != 0;
        #pragma unroll
        for (int m = 0; m < 2; ++m) {
            float send = hi ? r4[m] : r4[2 + m];
            float keep = hi ? r4[2 + m] : r4[m];
            r2[m] = keep + __shfl_xor(send, 2);
        }
    }

    const int c = cbase + q * 2;
    float* op = out + ((size_t)(b * N_ + ig)) * OD;
    *(float2*)(&op[c]) = make_float2(fmaf(r2[0], inv, bias[c]),
                                     fmaf(r2[1], inv, bias[c + 1]));
}

extern "C" void kernel_launch(void* const* d_in, const int* in_sizes, int n_in,
                              void* d_out, int out_size, void* d_ws, size_t ws_size,
                              hipStream_t stream) {
    const float* x    = (const float*)d_in[0];
    const int*   adj  = (const int*)d_in[1];
    const float* Wl   = (const float*)d_in[2];
    const float* bl   = (const float*)d_in[3];
    const float* Wr   = (const float*)d_in[4];
    const float* br   = (const float*)d_in[5];
    const float* att  = (const float*)d_in[6];
    const float* bias = (const float*)d_in[7];
    float* out = (float*)d_out;

    float* xl = (float*)d_ws;                    // 2 MB
    float* xr = xl + (size_t)B_ * N_ * OD;       // 2 MB
    float* dl = xr + (size_t)B_ * N_ * OD;       // 64 KB
    float* dr = dl + (size_t)B_ * N_ * H_;       // 64 KB

    proj_kernel<<<512, 256, 0, stream>>>(x, Wl, bl, Wr, br, att, xl, xr, dl, dr);
    attn_kernel<<<1024, 256, 0, stream>>>(adj, att, bias, xl, xr, dl, dr, out);
}